// Round 2
// baseline (177.686 us; speedup 1.0000x reference)
//
#include <hip/hip_runtime.h>

#define B  4
#define TE 512
#define TD 256
#define DE 512
#define U  128

// tanh(x) = 1 - 2/(exp2(x*2*log2e)+1); saturates correctly at +-inf, no NaN.
__device__ __forceinline__ float fast_tanh(float x){
    float e = __builtin_amdgcn_exp2f(x * 2.8853900817779268f);
    return 1.0f - 2.0f * __builtin_amdgcn_rcpf(e + 1.0f);
}

// P = X @ W + bias.  X:[B,T,512] f32, W:[512,128] f32, bias:[128] f32.
// TRANS=1: out[(b*U+u)*T + t]  (f32, transposed for score kernel)
// TRANS=0: out[(b*T+t)*U + u]  (f32)
template<int T, int TRANS>
__global__ __launch_bounds__(256) void proj_kernel(
        const float* __restrict__ X, const float* __restrict__ W,
        const float* __restrict__ bias, float* __restrict__ out){
    const int u  = threadIdx.x & 127;
    const int eh = threadIdx.x >> 7;          // 0 or 1
    const int nt = T / 8;
    const int b  = blockIdx.x / nt;
    const int e0 = (blockIdx.x % nt) * 8;

    const float* Xb = X + ((size_t)(b*T + e0)) * 512;
    const float* x0 = Xb + (size_t)(eh + 0) * 512;
    const float* x1 = Xb + (size_t)(eh + 2) * 512;
    const float* x2 = Xb + (size_t)(eh + 4) * 512;
    const float* x3 = Xb + (size_t)(eh + 6) * 512;

    float bse = bias[u];
    float acc0 = bse, acc1 = bse, acc2 = bse, acc3 = bse;

    #pragma unroll 8
    for (int d = 0; d < 512; ++d){
        float w = W[d*128 + u];                // coalesced across u-lanes
        acc0 += x0[d] * w;                     // broadcast (same addr all lanes in wave)
        acc1 += x1[d] * w;
        acc2 += x2[d] * w;
        acc3 += x3[d] * w;
    }

    if (TRANS){
        float* ob = out + ((size_t)(b*U + u)) * T + e0 + eh;
        ob[0] = acc0; ob[2] = acc1; ob[4] = acc2; ob[6] = acc3;
    } else {
        float* ob = out + ((size_t)(b*T + e0 + eh)) * U + u;
        ob[0] = acc0; ob[2*U] = acc1; ob[4*U] = acc2; ob[6*U] = acc3;
    }
}

// One block per (b,t): score_e = sum_u tanh(encT[b,u,e] + dec_p[b,t,u]) * V[u] + Vb
// then softmax over e (512), write f32 attn to d_out's second region.
__global__ __launch_bounds__(256) void score_kernel(
        const float* __restrict__ encT, const float* __restrict__ decp,
        const float* __restrict__ Vw, const float* __restrict__ Vb,
        float* __restrict__ attn_out){
    __shared__ float dp[U];
    __shared__ float vv[U];
    __shared__ float red[8];
    const int tid = threadIdx.x;
    const int b = blockIdx.x >> 8;     // Td = 256
    const int t = blockIdx.x & 255;

    if (tid < U){
        dp[tid] = decp[((size_t)(b*TD + t))*U + tid];
        vv[tid] = Vw[tid];
    }
    __syncthreads();

    const float* ep = encT + (size_t)b*U*TE + 2*tid;
    float s0 = 0.f, s1 = 0.f;
    #pragma unroll 4
    for (int u = 0; u < U; ++u){
        float2 e2 = *(const float2*)(ep + (size_t)u*TE);   // coalesced 8B
        float w = vv[u], d = dp[u];
        s0 += fast_tanh(e2.x + d) * w;
        s1 += fast_tanh(e2.y + d) * w;
    }
    float vb = Vb[0];
    s0 += vb; s1 += vb;

    // block max over 512 scores
    float m = fmaxf(s0, s1);
    for (int o = 32; o > 0; o >>= 1) m = fmaxf(m, __shfl_xor(m, o));
    const int wid = tid >> 6;
    if ((tid & 63) == 0) red[wid] = m;
    __syncthreads();
    m = fmaxf(fmaxf(red[0], red[1]), fmaxf(red[2], red[3]));

    float p0 = __builtin_amdgcn_exp2f((s0 - m) * 1.4426950408889634f);
    float p1 = __builtin_amdgcn_exp2f((s1 - m) * 1.4426950408889634f);
    float s = p0 + p1;
    for (int o = 32; o > 0; o >>= 1) s += __shfl_xor(s, o);
    if ((tid & 63) == 0) red[4 + wid] = s;
    __syncthreads();
    s = (red[4] + red[5]) + (red[6] + red[7]);
    float inv = __builtin_amdgcn_rcpf(s);

    float2 a; a.x = p0 * inv; a.y = p1 * inv;
    *(float2*)(attn_out + ((size_t)(b*TD + t))*TE + 2*tid) = a;
}

// context[b,t,d] = sum_e attn[b,t,e] * enc[b,e,d]; 4 t-rows per block.
__global__ __launch_bounds__(256) void context_kernel(
        const float* __restrict__ enc, const float* __restrict__ attn,
        float* __restrict__ ctx_out){
    __shared__ float at[4 * TE];
    const int tid = threadIdx.x;
    const int b  = blockIdx.x >> 6;
    const int tt = (blockIdx.x & 63) * 4;

    const float* ab = attn + ((size_t)(b*TD + tt)) * TE;   // 2048 contiguous f32
    #pragma unroll
    for (int j = 0; j < 2; ++j){
        int idx = j*256 + tid;
        float4 v = *(const float4*)(ab + idx*4);
        at[idx*4+0] = v.x; at[idx*4+1] = v.y;
        at[idx*4+2] = v.z; at[idx*4+3] = v.w;
    }
    __syncthreads();

    const int d0 = 2*tid;
    float a00=0,a01=0,a10=0,a11=0,a20=0,a21=0,a30=0,a31=0;
    const float* eb = enc + (size_t)b*TE*DE + d0;
    #pragma unroll 4
    for (int e = 0; e < TE; ++e){
        float2 x = *(const float2*)(eb + (size_t)e*DE);     // coalesced 8B
        float w0 = at[0*TE+e], w1 = at[1*TE+e], w2 = at[2*TE+e], w3 = at[3*TE+e];
        a00 += w0*x.x; a01 += w0*x.y;
        a10 += w1*x.x; a11 += w1*x.y;
        a20 += w2*x.x; a21 += w2*x.y;
        a30 += w3*x.x; a31 += w3*x.y;
    }

    float* ob = ctx_out + ((size_t)(b*TD + tt)) * DE + d0;
    *(float2*)(ob + 0*DE) = make_float2(a00, a01);
    *(float2*)(ob + 1*DE) = make_float2(a10, a11);
    *(float2*)(ob + 2*DE) = make_float2(a20, a21);
    *(float2*)(ob + 3*DE) = make_float2(a30, a31);
}

extern "C" void kernel_launch(void* const* d_in, const int* in_sizes, int n_in,
                              void* d_out, int out_size, void* d_ws, size_t ws_size,
                              hipStream_t stream){
    const float* enc = (const float*)d_in[0];
    const float* dec = (const float*)d_in[1];
    const float* W1w = (const float*)d_in[2];
    const float* W1b = (const float*)d_in[3];
    const float* W2w = (const float*)d_in[4];
    const float* W2b = (const float*)d_in[5];
    const float* Vw  = (const float*)d_in[6];
    const float* Vb  = (const float*)d_in[7];

    float* encT = (float*)d_ws;                       // B*U*TE f32 = 1 MB
    float* decp = encT + (size_t)B*U*TE;              // B*TD*U f32 = 0.5 MB

    float* outp     = (float*)d_out;                  // context region [B,TD,DE]
    float* attn_out = outp + (size_t)B*TD*DE;         // attn region [B,TD,TE]

    hipLaunchKernelGGL((proj_kernel<TE,1>), dim3(B*TE/8), dim3(256), 0, stream,
                       enc, W1w, W1b, encT);
    hipLaunchKernelGGL((proj_kernel<TD,0>), dim3(B*TD/8), dim3(256), 0, stream,
                       dec, W2w, W2b, decp);
    hipLaunchKernelGGL(score_kernel, dim3(B*TD), dim3(256), 0, stream,
                       encT, decp, Vw, Vb, attn_out);
    hipLaunchKernelGGL(context_kernel, dim3(B*TD/4), dim3(256), 0, stream,
                       enc, attn_out, outp);
}

// Round 3
// 144.909 us; speedup vs baseline: 1.2262x; 1.2262x over previous
//
#include <hip/hip_runtime.h>

#define B  4
#define TE 512
#define TD 256
#define DE 512
#define U  128

// tanh(x) = 1 - 2/(exp2(x*2*log2e)+1); saturates correctly at +-inf, no NaN.
__device__ __forceinline__ float fast_tanh(float x){
    float e = __builtin_amdgcn_exp2f(x * 2.8853900817779268f);
    return 1.0f - 2.0f * __builtin_amdgcn_rcpf(e + 1.0f);
}

// ---------------------------------------------------------------------------
// Fused projections: enc_p = enc@W1 + b1 (rows 0..2047), dec_p = dec@W2 + b2
// (rows 0..1023). 8 rows/block, natural [row][u] f32 output, all-float4 I/O.
// blocks 0..255 -> enc, 256..383 -> dec.
// ---------------------------------------------------------------------------
__global__ __launch_bounds__(256) void proj_fused_kernel(
        const float* __restrict__ enc, const float* __restrict__ dec,
        const float* __restrict__ W1w, const float* __restrict__ W1b,
        const float* __restrict__ W2w, const float* __restrict__ W2b,
        float* __restrict__ encp, float* __restrict__ decp){
    __shared__ float4 Xs[8 * 128];              // 8 rows x 512 f32 = 16 KB
    const int tid = threadIdx.x;

    const float *X, *W, *bias; float* out; int r0;
    if (blockIdx.x < 256){ r0 = blockIdx.x * 8;        X = enc; W = W1w; bias = W1b; out = encp; }
    else                 { r0 = (blockIdx.x - 256) * 8; X = dec; W = W2w; bias = W2b; out = decp; }

    // stage 8 rows of X (4096 floats = 1024 float4), coalesced
    const float4* Xg = (const float4*)(X + (size_t)r0 * 512);
    #pragma unroll
    for (int j = 0; j < 4; ++j)
        Xs[j * 256 + tid] = Xg[j * 256 + tid];
    __syncthreads();

    const int q = tid & 31;          // u-quad index: u0 = 4q
    const int g = tid >> 5;          // row within the 8-row tile
    const float4* W4 = (const float4*)W;   // row d = 32 float4

    float4 acc = ((const float4*)bias)[q];

    #pragma unroll 2
    for (int d0 = 0; d0 < 512; d0 += 4){
        float4 xr = Xs[g * 128 + (d0 >> 2)];       // X[r][d0..d0+3], LDS broadcast
        float4 w0 = W4[(d0 + 0) * 32 + q];
        float4 w1 = W4[(d0 + 1) * 32 + q];
        float4 w2 = W4[(d0 + 2) * 32 + q];
        float4 w3 = W4[(d0 + 3) * 32 + q];
        acc.x += xr.x*w0.x + xr.y*w1.x + xr.z*w2.x + xr.w*w3.x;
        acc.y += xr.x*w0.y + xr.y*w1.y + xr.z*w2.y + xr.w*w3.y;
        acc.z += xr.x*w0.z + xr.y*w1.z + xr.z*w2.z + xr.w*w3.z;
        acc.w += xr.x*w0.w + xr.y*w1.w + xr.z*w2.w + xr.w*w3.w;
    }

    ((float4*)out)[(size_t)(r0 + g) * 32 + q] = acc;   // coalesced float4 store
}

// ---------------------------------------------------------------------------
// Score + softmax: one block per (b, t-pair). Thread owns e-pair {2*tid, 2*tid+1}.
// score[t][e] = sum_u tanh(encp[b,e,u] + decp[b,t,u]) * V[u]   (+Vb cancels in
// softmax -> dropped). Writes f32 attn into d_out's second region.
// ---------------------------------------------------------------------------
__global__ __launch_bounds__(256) void score_kernel(
        const float* __restrict__ encp, const float* __restrict__ decp,
        const float* __restrict__ Vw, float* __restrict__ attn_out){
    __shared__ float4 dp[2 * 32];    // dec_p rows t0,t1 (2x128 f32)
    __shared__ float4 vv[32];        // V (128 f32)
    __shared__ float2 redm[4], reds[4];
    const int tid = threadIdx.x;
    const int b  = blockIdx.x >> 7;          // 128 t-pair blocks per b
    const int t0 = (blockIdx.x & 127) * 2;

    if (tid < 64)       dp[tid] = ((const float4*)decp)[(size_t)(b*TD + t0 + (tid>>5))*32 + (tid&31)];
    else if (tid < 96)  vv[tid - 64] = ((const float4*)Vw)[tid - 64];
    __syncthreads();

    const float4* pa = (const float4*)encp + (size_t)(b*TE + 2*tid) * 32;
    const float4* pb = pa + 32;
    float s00 = 0.f, s01 = 0.f, s10 = 0.f, s11 = 0.f;

    #pragma unroll 2
    for (int uq = 0; uq < 32; ++uq){
        float4 A  = pa[uq];
        float4 Bv = pb[uq];
        float4 D0 = dp[uq], D1 = dp[32 + uq], V = vv[uq];
        s00 += fast_tanh(A.x + D0.x)*V.x + fast_tanh(A.y + D0.y)*V.y
             + fast_tanh(A.z + D0.z)*V.z + fast_tanh(A.w + D0.w)*V.w;
        s01 += fast_tanh(Bv.x + D0.x)*V.x + fast_tanh(Bv.y + D0.y)*V.y
             + fast_tanh(Bv.z + D0.z)*V.z + fast_tanh(Bv.w + D0.w)*V.w;
        s10 += fast_tanh(A.x + D1.x)*V.x + fast_tanh(A.y + D1.y)*V.y
             + fast_tanh(A.z + D1.z)*V.z + fast_tanh(A.w + D1.w)*V.w;
        s11 += fast_tanh(Bv.x + D1.x)*V.x + fast_tanh(Bv.y + D1.y)*V.y
             + fast_tanh(Bv.z + D1.z)*V.z + fast_tanh(Bv.w + D1.w)*V.w;
    }

    // packed block-max over 512 e's for t0 (.x) and t1 (.y)
    float2 m = make_float2(fmaxf(s00, s01), fmaxf(s10, s11));
    for (int o = 32; o > 0; o >>= 1){
        m.x = fmaxf(m.x, __shfl_xor(m.x, o));
        m.y = fmaxf(m.y, __shfl_xor(m.y, o));
    }
    const int wid = tid >> 6;
    if ((tid & 63) == 0) redm[wid] = m;
    __syncthreads();
    m.x = fmaxf(fmaxf(redm[0].x, redm[1].x), fmaxf(redm[2].x, redm[3].x));
    m.y = fmaxf(fmaxf(redm[0].y, redm[1].y), fmaxf(redm[2].y, redm[3].y));

    const float L2E = 1.4426950408889634f;
    float p00 = __builtin_amdgcn_exp2f((s00 - m.x) * L2E);
    float p01 = __builtin_amdgcn_exp2f((s01 - m.x) * L2E);
    float p10 = __builtin_amdgcn_exp2f((s10 - m.y) * L2E);
    float p11 = __builtin_amdgcn_exp2f((s11 - m.y) * L2E);

    float2 s = make_float2(p00 + p01, p10 + p11);
    for (int o = 32; o > 0; o >>= 1){
        s.x += __shfl_xor(s.x, o);
        s.y += __shfl_xor(s.y, o);
    }
    if ((tid & 63) == 0) reds[wid] = s;
    __syncthreads();
    s.x = (reds[0].x + reds[1].x) + (reds[2].x + reds[3].x);
    s.y = (reds[0].y + reds[1].y) + (reds[2].y + reds[3].y);
    float inv0 = __builtin_amdgcn_rcpf(s.x);
    float inv1 = __builtin_amdgcn_rcpf(s.y);

    float2* a0 = (float2*)(attn_out + (size_t)(b*TD + t0    )*TE + 2*tid);
    float2* a1 = (float2*)(attn_out + (size_t)(b*TD + t0 + 1)*TE + 2*tid);
    *a0 = make_float2(p00 * inv0, p01 * inv0);
    *a1 = make_float2(p10 * inv1, p11 * inv1);
}

// ---------------------------------------------------------------------------
// context[b,t,d] = sum_e attn[b,t,e] * enc[b,e,d]; block = (b, t-quad),
// threads: (tid&127) -> d-quad, (tid>>7) -> e-half; LDS reduce across halves.
// ---------------------------------------------------------------------------
__global__ __launch_bounds__(256) void context_kernel(
        const float* __restrict__ enc, const float* __restrict__ attn,
        float* __restrict__ ctx_out){
    __shared__ float4 at[4 * 128];          // attn rows [t][e] as float4, 8 KB
    __shared__ float4 redc[128 * 5];        // 4 float4/thread, 20-pad rows, 10 KB
    const int tid = threadIdx.x;
    const int b  = blockIdx.x >> 6;
    const int tt = (blockIdx.x & 63) * 4;

    const float4* ag = (const float4*)(attn + (size_t)(b*TD + tt) * TE);
    at[tid]       = ag[tid];
    at[256 + tid] = ag[256 + tid];
    __syncthreads();

    const int dq = tid & 127;          // d0 = 4*dq
    const int eh = tid >> 7;           // e-half
    const float4* eb = (const float4*)enc + (size_t)(b*TE + eh*256) * 128 + dq;

    float4 acc0 = make_float4(0,0,0,0), acc1 = acc0, acc2 = acc0, acc3 = acc0;

    #pragma unroll 2
    for (int ec = 0; ec < 64; ++ec){
        const int eq = eh * 64 + ec;               // e-quad index within 512
        float4 w0 = at[0*128 + eq];
        float4 w1 = at[1*128 + eq];
        float4 w2 = at[2*128 + eq];
        float4 w3 = at[3*128 + eq];
        float4 x0 = eb[(ec*4 + 0) * 128];
        float4 x1 = eb[(ec*4 + 1) * 128];
        float4 x2 = eb[(ec*4 + 2) * 128];
        float4 x3 = eb[(ec*4 + 3) * 128];
        acc0.x += x0.x*w0.x + x1.x*w0.y + x2.x*w0.z + x3.x*w0.w;
        acc0.y += x0.y*w0.x + x1.y*w0.y + x2.y*w0.z + x3.y*w0.w;
        acc0.z += x0.z*w0.x + x1.z*w0.y + x2.z*w0.z + x3.z*w0.w;
        acc0.w += x0.w*w0.x + x1.w*w0.y + x2.w*w0.z + x3.w*w0.w;
        acc1.x += x0.x*w1.x + x1.x*w1.y + x2.x*w1.z + x3.x*w1.w;
        acc1.y += x0.y*w1.x + x1.y*w1.y + x2.y*w1.z + x3.y*w1.w;
        acc1.z += x0.z*w1.x + x1.z*w1.y + x2.z*w1.z + x3.z*w1.w;
        acc1.w += x0.w*w1.x + x1.w*w1.y + x2.w*w1.z + x3.w*w1.w;
        acc2.x += x0.x*w2.x + x1.x*w2.y + x2.x*w2.z + x3.x*w2.w;
        acc2.y += x0.y*w2.x + x1.y*w2.y + x2.y*w2.z + x3.y*w2.w;
        acc2.z += x0.z*w2.x + x1.z*w2.y + x2.z*w2.z + x3.z*w2.w;
        acc2.w += x0.w*w2.x + x1.w*w2.y + x2.w*w2.z + x3.w*w2.w;
        acc3.x += x0.x*w3.x + x1.x*w3.y + x2.x*w3.z + x3.x*w3.w;
        acc3.y += x0.y*w3.x + x1.y*w3.y + x2.y*w3.z + x3.y*w3.w;
        acc3.z += x0.z*w3.x + x1.z*w3.y + x2.z*w3.z + x3.z*w3.w;
        acc3.w += x0.w*w3.x + x1.w*w3.y + x2.w*w3.z + x3.w*w3.w;
    }

    if (eh == 1){
        redc[dq*5 + 0] = acc0; redc[dq*5 + 1] = acc1;
        redc[dq*5 + 2] = acc2; redc[dq*5 + 3] = acc3;
    }
    __syncthreads();
    if (eh == 0){
        float4 b0 = redc[dq*5+0], b1 = redc[dq*5+1], b2 = redc[dq*5+2], b3 = redc[dq*5+3];
        acc0.x += b0.x; acc0.y += b0.y; acc0.z += b0.z; acc0.w += b0.w;
        acc1.x += b1.x; acc1.y += b1.y; acc1.z += b1.z; acc1.w += b1.w;
        acc2.x += b2.x; acc2.y += b2.y; acc2.z += b2.z; acc2.w += b2.w;
        acc3.x += b3.x; acc3.y += b3.y; acc3.z += b3.z; acc3.w += b3.w;
        float4* ob = (float4*)ctx_out + (size_t)(b*TD + tt) * 128 + dq;
        ob[0*128] = acc0; ob[1*128] = acc1; ob[2*128] = acc2; ob[3*128] = acc3;
    }
}

extern "C" void kernel_launch(void* const* d_in, const int* in_sizes, int n_in,
                              void* d_out, int out_size, void* d_ws, size_t ws_size,
                              hipStream_t stream){
    const float* enc = (const float*)d_in[0];
    const float* dec = (const float*)d_in[1];
    const float* W1w = (const float*)d_in[2];
    const float* W1b = (const float*)d_in[3];
    const float* W2w = (const float*)d_in[4];
    const float* W2b = (const float*)d_in[5];
    const float* Vw  = (const float*)d_in[6];

    float* encp = (float*)d_ws;                       // [B*TE,128] f32 = 1 MB
    float* decp = encp + (size_t)B*TE*U;              // [B*TD,128] f32 = 0.5 MB

    float* outp     = (float*)d_out;                  // context [B,TD,DE]
    float* attn_out = outp + (size_t)B*TD*DE;         // attn    [B,TD,TE]

    hipLaunchKernelGGL(proj_fused_kernel, dim3(384), dim3(256), 0, stream,
                       enc, dec, W1w, W1b, W2w, W2b, encp, decp);
    hipLaunchKernelGGL(score_kernel, dim3(B*TD/2), dim3(256), 0, stream,
                       encp, decp, Vw, attn_out);
    hipLaunchKernelGGL(context_kernel, dim3(B*TD/4), dim3(256), 0, stream,
                       enc, attn_out, outp);
}

// Round 4
// 135.060 us; speedup vs baseline: 1.3156x; 1.0729x over previous
//
#include <hip/hip_runtime.h>

#define B  4
#define TE 512
#define TD 256
#define DE 512
#define U  128

// tanh(x) = 1 - 2/(exp2(x*2*log2e)+1); saturates correctly at +-inf, no NaN.
__device__ __forceinline__ float fast_tanh(float x){
    float e = __builtin_amdgcn_exp2f(x * 2.8853900817779268f);
    return 1.0f - 2.0f * __builtin_amdgcn_rcpf(e + 1.0f);
}

// ---------------------------------------------------------------------------
// Fused projections. blocks 0..255: enc_p = enc@W1+b1, output TRANSPOSED as
// encT[b][u][e] (via LDS transpose; both global sides coalesced).
// blocks 256..383: dec_p = dec@W2+b2, natural [t][u] layout.
// 8 rows/block, 256 threads.
// ---------------------------------------------------------------------------
__global__ __launch_bounds__(256) void proj_fused_kernel(
        const float* __restrict__ enc, const float* __restrict__ dec,
        const float* __restrict__ W1w, const float* __restrict__ W1b,
        const float* __restrict__ W2w, const float* __restrict__ W2b,
        float* __restrict__ encT, float* __restrict__ decp){
    __shared__ float4 Xs[8 * 128];              // 8 rows x 512 f32 = 16 KB
    float* T = (float*)Xs;                      // aliased transpose buffer
    const int tid = threadIdx.x;

    const bool is_enc = blockIdx.x < 256;
    const float *X, *W, *bias; int r0;
    if (is_enc){ r0 = blockIdx.x * 8;         X = enc; W = W1w; bias = W1b; }
    else       { r0 = (blockIdx.x - 256) * 8; X = dec; W = W2w; bias = W2b; }

    // stage 8 rows of X (1024 float4), coalesced
    const float4* Xg = (const float4*)(X + (size_t)r0 * 512);
    #pragma unroll
    for (int j = 0; j < 4; ++j)
        Xs[j * 256 + tid] = Xg[j * 256 + tid];
    __syncthreads();

    const int q = tid & 31;          // u-quad index: u0 = 4q
    const int g = tid >> 5;          // row within the 8-row tile
    const float4* W4 = (const float4*)W;   // row d = 32 float4

    float4 acc = ((const float4*)bias)[q];

    #pragma unroll 2
    for (int d0 = 0; d0 < 512; d0 += 4){
        float4 xr = Xs[g * 128 + (d0 >> 2)];       // LDS broadcast
        float4 w0 = W4[(d0 + 0) * 32 + q];
        float4 w1 = W4[(d0 + 1) * 32 + q];
        float4 w2 = W4[(d0 + 2) * 32 + q];
        float4 w3 = W4[(d0 + 3) * 32 + q];
        acc.x += xr.x*w0.x + xr.y*w1.x + xr.z*w2.x + xr.w*w3.x;
        acc.y += xr.x*w0.y + xr.y*w1.y + xr.z*w2.y + xr.w*w3.y;
        acc.z += xr.x*w0.z + xr.y*w1.z + xr.z*w2.z + xr.w*w3.z;
        acc.w += xr.x*w0.w + xr.y*w1.w + xr.z*w2.w + xr.w*w3.w;
    }

    if (is_enc){
        __syncthreads();                           // Xs reads complete
        // T[u][e_local], u-stride 9 (pad breaks power-of-2 banks)
        T[(4*q + 0)*9 + g] = acc.x;
        T[(4*q + 1)*9 + g] = acc.y;
        T[(4*q + 2)*9 + g] = acc.z;
        T[(4*q + 3)*9 + g] = acc.w;
        __syncthreads();
        if (tid < 128){
            const int u  = tid;
            const int b  = r0 >> 9;        // 512 rows per batch
            const int et = r0 & 511;       // e-tile base
            float4 lo = make_float4(T[u*9+0], T[u*9+1], T[u*9+2], T[u*9+3]);
            float4 hi = make_float4(T[u*9+4], T[u*9+5], T[u*9+6], T[u*9+7]);
            float4* row = (float4*)encT + (size_t)(b*U + u)*128 + (et >> 2);
            row[0] = lo; row[1] = hi;
        }
    } else {
        ((float4*)decp)[(size_t)(r0 + g) * 32 + q] = acc;   // coalesced
    }
}

// ---------------------------------------------------------------------------
// Score + softmax. block = (b, t-pair), 256 threads: t = tid>>7, e-quad = tid&127.
// encT[b][u][e] -> coalesced float4 loads across e-lanes. Vb cancels in softmax.
// ---------------------------------------------------------------------------
__global__ __launch_bounds__(256) void score_kernel(
        const float* __restrict__ encT, const float* __restrict__ decp,
        const float* __restrict__ Vw, float* __restrict__ attn_out){
    __shared__ float4 dp4[64];       // dec_p rows t0,t1 (2 x 128 f32)
    __shared__ float4 vv4[32];       // V (128 f32)
    __shared__ float redm[4], reds[4];
    const float* dpf = (const float*)dp4;
    const float* vvf = (const float*)vv4;
    const int tid = threadIdx.x;
    const int b  = blockIdx.x >> 7;
    const int t0 = (blockIdx.x & 127) * 2;

    if (tid < 64)       dp4[tid] = ((const float4*)decp)[(size_t)(b*TD + t0 + (tid>>5))*32 + (tid&31)];
    else if (tid < 96)  vv4[tid - 64] = ((const float4*)Vw)[tid - 64];
    __syncthreads();

    const int t  = tid >> 7;         // 0 or 1
    const int eq = tid & 127;        // e-quad: e0 = 4*eq
    const float4* E = (const float4*)encT + (size_t)b*U*128 + eq;

    float4 s = make_float4(0.f, 0.f, 0.f, 0.f);
    #pragma unroll 4
    for (int u = 0; u < U; ++u){
        float4 A = E[(size_t)u * 128];        // coalesced across e-lanes
        float d = dpf[t*128 + u];
        float v = vvf[u];
        s.x += fast_tanh(A.x + d) * v;
        s.y += fast_tanh(A.y + d) * v;
        s.z += fast_tanh(A.z + d) * v;
        s.w += fast_tanh(A.w + d) * v;
    }

    // softmax over 512 e's per t (t spans 2 waves)
    float m = fmaxf(fmaxf(s.x, s.y), fmaxf(s.z, s.w));
    for (int o = 32; o > 0; o >>= 1) m = fmaxf(m, __shfl_xor(m, o));
    const int w = tid >> 6;
    if ((tid & 63) == 0) redm[w] = m;
    __syncthreads();
    m = fmaxf(redm[2*t], redm[2*t + 1]);

    const float L2E = 1.4426950408889634f;
    float4 p;
    p.x = __builtin_amdgcn_exp2f((s.x - m) * L2E);
    p.y = __builtin_amdgcn_exp2f((s.y - m) * L2E);
    p.z = __builtin_amdgcn_exp2f((s.z - m) * L2E);
    p.w = __builtin_amdgcn_exp2f((s.w - m) * L2E);
    float sl = (p.x + p.y) + (p.z + p.w);
    for (int o = 32; o > 0; o >>= 1) sl += __shfl_xor(sl, o);
    if ((tid & 63) == 0) reds[w] = sl;
    __syncthreads();
    float inv = __builtin_amdgcn_rcpf(reds[2*t] + reds[2*t + 1]);

    p.x *= inv; p.y *= inv; p.z *= inv; p.w *= inv;
    ((float4*)attn_out)[(size_t)(b*TD + t0 + t)*128 + eq] = p;
}

// ---------------------------------------------------------------------------
// context[b,t,d] = sum_e attn[b,t,e]*enc[b,e,d].
// block = (b, t-oct, d-half), 512 threads: dq = tid&63 (d-quad within half),
// eq = tid>>6 (e-eighth, 64 e's each). XCD-swizzled so each XCD works one b.
// LDS tree-reduce over the 8 e-groups.
// ---------------------------------------------------------------------------
__global__ __launch_bounds__(512) void context_kernel(
        const float* __restrict__ enc, const float* __restrict__ attn,
        float* __restrict__ ctx_out){
    __shared__ float4 at4[8 * 128];      // attn rows [t][e-quad], 16 KB
    __shared__ float4 red4[8 * 256];     // reduce buffer [t][4 groups][64], 32 KB
    const int tid = threadIdx.x;
    const int dh = blockIdx.x & 1;             // d-half
    const int b  = (blockIdx.x >> 1) & 3;      // ~XCD-resident batch
    const int t0 = (blockIdx.x >> 3) * 8;      // t-oct
    const int dq = tid & 63;
    const int eq = tid >> 6;

    // stage 8 attn rows (1024 float4), coalesced
    const float4* A4 = (const float4*)(attn + (size_t)(b*TD + t0) * TE);
    at4[tid]       = A4[tid];
    at4[tid + 512] = A4[tid + 512];
    __syncthreads();

    float4 acc[8];
    #pragma unroll
    for (int t = 0; t < 8; ++t) acc[t] = make_float4(0.f, 0.f, 0.f, 0.f);

    const float4* eb = (const float4*)enc + (size_t)(b*TE)*128 + dh*64 + dq;
    for (int ec = 0; ec < 16; ++ec){
        const int e0 = eq*64 + ec*4;
        float4 x0 = eb[(size_t)(e0 + 0) * 128];
        float4 x1 = eb[(size_t)(e0 + 1) * 128];
        float4 x2 = eb[(size_t)(e0 + 2) * 128];
        float4 x3 = eb[(size_t)(e0 + 3) * 128];
        #pragma unroll
        for (int t = 0; t < 8; ++t){
            float4 w = at4[t*128 + (e0 >> 2)];     // wave-uniform broadcast
            acc[t].x += x0.x*w.x + x1.x*w.y + x2.x*w.z + x3.x*w.w;
            acc[t].y += x0.y*w.x + x1.y*w.y + x2.y*w.z + x3.y*w.w;
            acc[t].z += x0.z*w.x + x1.z*w.y + x2.z*w.z + x3.z*w.w;
            acc[t].w += x0.w*w.x + x1.w*w.y + x2.w*w.z + x3.w*w.w;
        }
    }

    // tree-reduce over eq = 8 -> 1
    for (int step = 4; step >= 1; step >>= 1){
        if (eq >= step && eq < 2*step){
            #pragma unroll
            for (int t = 0; t < 8; ++t)
                red4[t*256 + (eq - step)*64 + dq] = acc[t];
        }
        __syncthreads();
        if (eq < step){
            #pragma unroll
            for (int t = 0; t < 8; ++t){
                float4 r = red4[t*256 + eq*64 + dq];
                acc[t].x += r.x; acc[t].y += r.y; acc[t].z += r.z; acc[t].w += r.w;
            }
        }
        __syncthreads();
    }

    if (eq == 0){
        float4* ob = (float4*)ctx_out + (size_t)(b*TD + t0)*128 + dh*64 + dq;
        #pragma unroll
        for (int t = 0; t < 8; ++t) ob[t*128] = acc[t];
    }
}

extern "C" void kernel_launch(void* const* d_in, const int* in_sizes, int n_in,
                              void* d_out, int out_size, void* d_ws, size_t ws_size,
                              hipStream_t stream){
    const float* enc = (const float*)d_in[0];
    const float* dec = (const float*)d_in[1];
    const float* W1w = (const float*)d_in[2];
    const float* W1b = (const float*)d_in[3];
    const float* W2w = (const float*)d_in[4];
    const float* W2b = (const float*)d_in[5];
    const float* Vw  = (const float*)d_in[6];

    float* encT = (float*)d_ws;                       // [B,U,TE] f32 = 1 MB
    float* decp = encT + (size_t)B*U*TE;              // [B*TD,U] f32 = 0.5 MB

    float* outp     = (float*)d_out;                  // context [B,TD,DE]
    float* attn_out = outp + (size_t)B*TD*DE;         // attn    [B,TD,TE]

    hipLaunchKernelGGL(proj_fused_kernel, dim3(384), dim3(256), 0, stream,
                       enc, dec, W1w, W1b, W2w, W2b, encT, decp);
    hipLaunchKernelGGL(score_kernel, dim3(B*TD/2), dim3(256), 0, stream,
                       encT, decp, Vw, attn_out);
    hipLaunchKernelGGL(context_kernel, dim3(B*TD/8*2), dim3(512), 0, stream,
                       enc, attn_out, outp);
}